// Round 14
// baseline (242.729 us; speedup 1.0000x reference)
//
#include <hip/hip_runtime.h>

// DepthFlowProjectionModule — B=4, H=1080, W=1920, fp32.
// Round 14: split the 97us norm_fill (1.78 TB/s, divide+divergence-bound)
// into (a) norm_stream: branchless float4 streaming normalize (1 rcp + 2 mul
// per px), holes -> block-aggregated compact list (R9 pattern); (b)
// fill_holes: sparse pass over ~150K holes only. Splat (R13 4-px vectorized,
// u64-packed 2-LDS-atomic deposit) and scatter_far unchanged.

#define TW 80
#define TH 60
#define AW 81             // A-plane cols  (x0-1 .. x0+TW-1)
#define AH 61             // A-plane rows  (y0-1 .. y0+TH-1)
#define APIX (AW * AH)    // 4941 cells; u64 plane + f32 plane = 59292 B LDS
#define EW 128            // read region: gx in [x0-24, x0+103]
#define EH 112            // read region: gy in [y0-26, y0+85]
#define RX 24
#define RY 26
#define DXLO (-24)
#define DXHI 23
#define DYLO (-26)
#define DYHI 25
#define BLK 1024
#define FCAP 256          // LDS far-record staging (expected ~26/block)
#define FPSCALE 1048576.0f           // 2^20
#define FPINV   9.5367431640625e-7f  // 2^-20
#define FARCAP 400000     // global far-list capacity (expected ~45K)
#define HCAP   1500000    // global hole-list capacity (expected ~150K)

__global__ __launch_bounds__(BLK, 2) void splat_box(
    const float* __restrict__ flow, const float* __restrict__ depth,
    float* __restrict__ cnt_all, float* __restrict__ sx_all,
    float* __restrict__ sy_all,
    unsigned* __restrict__ counter, float4* __restrict__ list, int cap,
    int B, int H, int W)
{
    __shared__ unsigned long long lpk[APIX];   // (sx_fixed<<32)|sy_fixed, biased
    __shared__ float lcf[APIX];                // cnt = sum of m*w
    __shared__ float4 fstage[FCAP];
    __shared__ unsigned fcnt, fbase;

    int tid = threadIdx.x;
    for (int q = tid; q < APIX; q += BLK) { lpk[q] = 0ULL; lcf[q] = 0.0f; }
    if (tid == 0) fcnt = 0;
    __syncthreads();

    int x0 = blockIdx.x * TW;
    int y0 = blockIdx.y * TH;
    int b  = blockIdx.z;
    int HWp = H * W;
    const float* fb = flow + (size_t)b * 2 * HWp;
    const float* db = depth + (size_t)b * HWp;
    float* cm  = cnt_all + (size_t)b * HWp;
    float* sxm = sx_all + (size_t)b * HWp;
    float* sym = sy_all + (size_t)b * HWp;

    // 4 px per thread: 32 col-groups x 32 rows per k-iteration
    int cg = tid & 31;            // column group (4 px each)
    int rr = tid >> 5;            // row within the 32-row slab
    int gx0 = x0 - RX + cg * 4;   // group base col (multiple of 4)
    bool gx_ok = (unsigned)gx0 < (unsigned)W;   // whole group in/out (W%4==0)

    #pragma unroll
    for (int k = 0; k < 4; ++k) {
        int ey = k * 32 + rr;
        if (ey >= EH) continue;                 // only k=3, rr>=16
        int gy = y0 - RY + ey;
        if (!gx_ok || (unsigned)gy >= (unsigned)H) continue;
        int p = gy * W + gx0;
        float4 fx4 = *(const float4*)(fb + p);
        float4 fy4 = *(const float4*)(fb + HWp + p);
        float4 w4  = *(const float4*)(db + p);
        const float* fxp = (const float*)&fx4;
        const float* fyp = (const float*)&fy4;
        const float* wp  = (const float*)&w4;
        #pragma unroll
        for (int j = 0; j < 4; ++j) {
            int gx = gx0 + j;
            float fx = fxp[j], fy = fyp[j];
            float x2 = (float)gx + fx;
            float y2 = (float)gy + fy;
            if (!(x2 >= 0.0f && y2 >= 0.0f &&
                  x2 <= (float)(W - 1) && y2 <= (float)(H - 1)))
                continue;
            float w = wp[j];
            int ixL = min((int)x2, W - 1);  // x2>=0 -> trunc == floor == astype+clip
            int iyT = min((int)y2, H - 1);
            int dx = ixL - gx;
            int dy = iyT - gy;
            bool near = (dx >= DXLO) & (dx <= DXHI) & (dy >= DYLO) & (dy <= DYHI);
            if (near) {
                int ax = ixL - (x0 - 1);
                int ay = iyT - (y0 - 1);
                if ((unsigned)ax < (unsigned)AW && (unsigned)ay < (unsigned)AH) {
                    float m = ((ixL == W - 1) ? 2.0f : 1.0f) *
                              ((iyT == H - 1) ? 2.0f : 1.0f);
                    float mw = m * w;
                    // biased-positive fixed point; near => |fx|<24, |fy|<26 < 32
                    unsigned ux = __float2uint_rn((32.0f - fx) * mw * FPSCALE);
                    unsigned uy = __float2uint_rn((32.0f - fy) * mw * FPSCALE);
                    int l = ay * AW + ax;
                    atomicAdd(&lpk[l], ((unsigned long long)ux << 32) | uy);
                    atomicAdd(&lcf[l], mw);
                }
            } else if (((unsigned)(gx - x0) < (unsigned)TW) &&
                       ((unsigned)(gy - y0) < (unsigned)TH)) {
                // far tail: stage in LDS (per-CU atomic); global fallback if full
                unsigned key = (unsigned)ixL | ((unsigned)iyT << 11) |
                               ((unsigned)b << 22);
                float4 rec = make_float4(__uint_as_float(key), w, -fx * w, -fy * w);
                unsigned li = atomicAdd(&fcnt, 1u);
                if (li < FCAP) {
                    fstage[li] = rec;
                } else {
                    unsigned gi = atomicAdd(counter, 1u);
                    if (gi < (unsigned)cap) list[gi] = rec;
                }
            }
        }
    }
    __syncthreads();

    // reserve one contiguous chunk for this block's staged far records
    if (tid == 0) {
        unsigned n = min(fcnt, (unsigned)FCAP);
        fbase = atomicAdd(counter, n);
    }
    __syncthreads();
    unsigned nst = min(fcnt, (unsigned)FCAP);
    for (unsigned q = tid; q < nst; q += BLK) {
        unsigned gi = fbase + q;
        if (gi < (unsigned)cap) list[gi] = fstage[q];
    }

    // flush: per-cell debias (exact via cnt), then 2x2 box-sum; exclusive store
    for (int q = tid; q < TW * TH; q += BLK) {
        int oyy = q / TW;
        int oxx = q - oyy * TW;
        int base = (oyy + 1) * AW + (oxx + 1);
        float c = 0.0f, sx = 0.0f, sy = 0.0f;
        #pragma unroll
        for (int j = 0; j < 4; ++j) {
            int l = base - (j & 1) - (j >> 1) * AW;
            unsigned long long pk = lpk[l];
            float cc = lcf[l];
            float bias = 32.0f * cc;
            c  += cc;
            sx += (float)(unsigned)(pk >> 32) * FPINV - bias;
            sy += (float)(unsigned)(pk & 0xFFFFFFFFULL) * FPINV - bias;
        }
        int g = (y0 + oyy) * W + x0 + oxx;
        cm[g]  = c;
        sxm[g] = sx;
        sym[g] = sy;
    }
}

__global__ void scatter_far(const float4* __restrict__ list,
                            const unsigned* __restrict__ counter, int cap,
                            float* __restrict__ cnt_all, float* __restrict__ sx_all,
                            float* __restrict__ sy_all, int HWp, int W, int H)
{
    unsigned n = min(counter[0], (unsigned)cap);
    for (unsigned i = blockIdx.x * blockDim.x + threadIdx.x; i < n;
         i += gridDim.x * blockDim.x) {
        float4 e = list[i];
        unsigned key = __float_as_uint(e.x);
        int x = key & 2047u;
        int y = (key >> 11) & 2047u;
        int b = key >> 22;
        int ixR = min(x + 1, W - 1);
        int iyB = min(y + 1, H - 1);
        size_t base = (size_t)b * HWp;
        int i00 = y * W + x,   i01 = y * W + ixR;
        int i10 = iyB * W + x, i11 = iyB * W + ixR;
        atomicAdd(&cnt_all[base + i00], e.y);
        atomicAdd(&cnt_all[base + i01], e.y);
        atomicAdd(&cnt_all[base + i10], e.y);
        atomicAdd(&cnt_all[base + i11], e.y);
        atomicAdd(&sx_all[base + i00], e.z);
        atomicAdd(&sx_all[base + i01], e.z);
        atomicAdd(&sx_all[base + i10], e.z);
        atomicAdd(&sx_all[base + i11], e.z);
        atomicAdd(&sy_all[base + i00], e.w);
        atomicAdd(&sy_all[base + i01], e.w);
        atomicAdd(&sy_all[base + i10], e.w);
        atomicAdd(&sy_all[base + i11], e.w);
    }
}

// branchless streaming normalize; holes -> 0 + compact list (block-aggregated)
__global__ void norm_stream(const float* __restrict__ cnt_all,
                            const float* __restrict__ sx_all,
                            const float* __restrict__ sy_all,
                            float* __restrict__ out,
                            unsigned* __restrict__ hcounter,
                            unsigned* __restrict__ hlist, int hcap,
                            int B, int H, int W)
{
    __shared__ unsigned hstage[1024];   // max 4 px * 256 thr, can't overflow
    __shared__ unsigned hcnt_s, hbase;
    int tid = threadIdx.x;
    if (tid == 0) hcnt_s = 0;
    __syncthreads();

    int HWp = H * W;
    int total = B * HWp;
    int i4 = (blockIdx.x * 256 + tid) * 4;
    if (i4 < total) {
        int b = i4 / HWp;
        int r = i4 - b * HWp;          // HWp%4==0 -> all 4 px in same batch
        const float* cb  = cnt_all + (size_t)b * HWp;
        const float* sxb = sx_all + (size_t)b * HWp;
        const float* syb = sy_all + (size_t)b * HWp;
        float4 c4 = *(const float4*)(cb + r);
        float4 x4 = *(const float4*)(sxb + r);
        float4 y4 = *(const float4*)(syb + r);
        const float* cp = (const float*)&c4;
        const float* xp = (const float*)&x4;
        const float* yp = (const float*)&y4;
        float rx[4], ry[4];
        #pragma unroll
        for (int j = 0; j < 4; ++j) {
            float c = cp[j];
            bool cov = c > 0.0f;
            float inv = cov ? 1.0f / c : 0.0f;   // 1 div, 2 mul per px
            rx[j] = xp[j] * inv;
            ry[j] = yp[j] * inv;
            if (!cov) hstage[atomicAdd(&hcnt_s, 1u)] = (unsigned)(i4 + j);
        }
        float* ob = out + (size_t)b * 2 * HWp;
        *(float4*)(ob + r)       = make_float4(rx[0], rx[1], rx[2], rx[3]);
        *(float4*)(ob + HWp + r) = make_float4(ry[0], ry[1], ry[2], ry[3]);
    }
    __syncthreads();
    if (tid == 0) hbase = atomicAdd(hcounter, hcnt_s);
    __syncthreads();
    unsigned n = hcnt_s;
    for (unsigned q = tid; q < n; q += 256) {
        unsigned gi = hbase + q;
        if (gi < (unsigned)hcap) hlist[gi] = hstage[q];
    }
}

// sparse hole fill: one thread per hole, 4-direction nearest-covered average
__global__ void fill_holes(const unsigned* __restrict__ hlist,
                           const unsigned* __restrict__ hcounter, int hcap,
                           const float* __restrict__ cnt_all,
                           const float* __restrict__ sx_all,
                           const float* __restrict__ sy_all,
                           float* __restrict__ out,
                           int B, int H, int W)
{
    int HWp = H * W;
    unsigned n = min(hcounter[0], (unsigned)hcap);
    for (unsigned t = blockIdx.x * blockDim.x + threadIdx.x; t < n;
         t += gridDim.x * blockDim.x) {
        unsigned i = hlist[t];
        int b = i / HWp;
        int r = i - b * HWp;
        int y = r / W;
        int x = r - y * W;
        const float* cb  = cnt_all + (size_t)b * HWp;
        const float* sxb = sx_all + (size_t)b * HWp;
        const float* syb = sy_all + (size_t)b * HWp;
        float nx = 0.0f, ny = 0.0f;
        int den = 0;
        for (int xx = x - 1; xx >= 0; --xx) {
            int q = y * W + xx; float cq = cb[q];
            if (cq > 0.0f) { nx += sxb[q] / cq; ny += syb[q] / cq; ++den; break; }
        }
        for (int xx = x + 1; xx < W; ++xx) {
            int q = y * W + xx; float cq = cb[q];
            if (cq > 0.0f) { nx += sxb[q] / cq; ny += syb[q] / cq; ++den; break; }
        }
        for (int yy = y - 1; yy >= 0; --yy) {
            int q = yy * W + x; float cq = cb[q];
            if (cq > 0.0f) { nx += sxb[q] / cq; ny += syb[q] / cq; ++den; break; }
        }
        for (int yy = y + 1; yy < H; ++yy) {
            int q = yy * W + x; float cq = cb[q];
            if (cq > 0.0f) { nx += sxb[q] / cq; ny += syb[q] / cq; ++den; break; }
        }
        if (den > 0) {
            float fd = (float)den;
            float* ob = out + (size_t)b * 2 * HWp;
            ob[r] = nx / fd;
            ob[HWp + r] = ny / fd;
        }
        // den==0: out already 0 from norm_stream (matches reference)
    }
}

// fallback (ws too small / shape mismatch): global atomics + monolithic pass
__global__ void splat_naive_ws(const float* __restrict__ flow,
                               const float* __restrict__ depth,
                               float* __restrict__ cnt_all,
                               float* __restrict__ sx_all,
                               float* __restrict__ sy_all,
                               int B, int H, int W)
{
    int i = blockIdx.x * blockDim.x + threadIdx.x;
    int HWp = H * W;
    if (i >= B * HWp) return;
    int b = i / HWp;
    int p = i - b * HWp;
    int y = p / W;
    int x = p - y * W;
    const float* fb = flow + (size_t)b * 2 * HWp;
    float fx = fb[p], fy = fb[HWp + p];
    float x2 = (float)x + fx, y2 = (float)y + fy;
    if (!(x2 >= 0.0f && y2 >= 0.0f && x2 <= (float)(W - 1) && y2 <= (float)(H - 1)))
        return;
    float w = depth[i];
    int ixL = min((int)x2, W - 1);
    int iyT = min((int)y2, H - 1);
    int ixR = min(ixL + 1, W - 1);
    int iyB = min(iyT + 1, H - 1);
    float ax = -fx * w, ay = -fy * w;
    size_t base = (size_t)b * HWp;
    int idx[4] = {iyT * W + ixL, iyT * W + ixR, iyB * W + ixL, iyB * W + ixR};
    #pragma unroll
    for (int c = 0; c < 4; ++c) {
        atomicAdd(&cnt_all[base + idx[c]], w);
        atomicAdd(&sx_all[base + idx[c]], ax);
        atomicAdd(&sy_all[base + idx[c]], ay);
    }
}

__global__ void norm_fill_mono(const float* __restrict__ cnt_all,
                               const float* __restrict__ sx_all,
                               const float* __restrict__ sy_all,
                               float* __restrict__ out,
                               int B, int H, int W)
{
    int i = blockIdx.x * blockDim.x + threadIdx.x;
    int HWp = H * W;
    if (i >= B * HWp) return;
    int b = i / HWp;
    int r = i - b * HWp;
    float c = cnt_all[i];
    float rx, ry;
    if (c > 0.0f) {
        rx = sx_all[i] / c;
        ry = sy_all[i] / c;
    } else {
        int y = r / W;
        int x = r - y * W;
        const float* cb  = cnt_all + (size_t)b * HWp;
        const float* sxb = sx_all + (size_t)b * HWp;
        const float* syb = sy_all + (size_t)b * HWp;
        float nx = 0.0f, ny = 0.0f;
        int den = 0;
        for (int xx = x - 1; xx >= 0; --xx) {
            int q = y * W + xx; float cq = cb[q];
            if (cq > 0.0f) { nx += sxb[q] / cq; ny += syb[q] / cq; ++den; break; }
        }
        for (int xx = x + 1; xx < W; ++xx) {
            int q = y * W + xx; float cq = cb[q];
            if (cq > 0.0f) { nx += sxb[q] / cq; ny += syb[q] / cq; ++den; break; }
        }
        for (int yy = y - 1; yy >= 0; --yy) {
            int q = yy * W + x; float cq = cb[q];
            if (cq > 0.0f) { nx += sxb[q] / cq; ny += syb[q] / cq; ++den; break; }
        }
        for (int yy = y + 1; yy < H; ++yy) {
            int q = yy * W + x; float cq = cb[q];
            if (cq > 0.0f) { nx += sxb[q] / cq; ny += syb[q] / cq; ++den; break; }
        }
        if (den > 0) { float fd = (float)den; rx = nx / fd; ry = ny / fd; }
        else         { rx = 0.0f; ry = 0.0f; }
    }
    float* ob = out + (size_t)b * 2 * HWp;
    ob[r] = rx;
    ob[HWp + r] = ry;
}

extern "C" void kernel_launch(void* const* d_in, const int* in_sizes, int n_in,
                              void* d_out, int out_size, void* d_ws, size_t ws_size,
                              hipStream_t stream) {
    const float* flow  = (const float*)d_in[0];   // (B,2,H,W)
    const float* depth = (const float*)d_in[1];   // (B,1,H,W)
    float* out = (float*)d_out;                   // (B,2,H,W)

    const int H = 1080, W = 1920;
    const int HWp = H * W;
    const int B = in_sizes[1] / HWp;
    const size_t plane = (size_t)B * HWp;

    // ws: [cnt][sx][sy][256B counters][far list FARCAP*16B][hole list HCAP*4B]
    float* cnt_all = (float*)d_ws;
    float* sx_all  = cnt_all + plane;
    float* sy_all  = cnt_all + 2 * plane;
    unsigned* counter = (unsigned*)(cnt_all + 3 * plane);  // [0]=far, [32]=hole
    float4* list = (float4*)((char*)counter + 256);
    unsigned* hlist = (unsigned*)((char*)list + (size_t)FARCAP * 16);
    size_t need = 3 * plane * sizeof(float) + 256 +
                  (size_t)FARCAP * 16 + (size_t)HCAP * 4;

    int blocks = (int)((plane + 255) / 256);
    bool tiled = (ws_size >= need) && (W % TW == 0) && (H % TH == 0) && (W % 4 == 0);

    if (tiled) {
        hipMemsetAsync(counter, 0, 256, stream);   // far + hole counters
        dim3 grid(W / TW, H / TH, B);              // 24 x 18 x 4
        splat_box<<<grid, BLK, 0, stream>>>(flow, depth, cnt_all, sx_all, sy_all,
                                            counter, list, FARCAP, B, H, W);
        scatter_far<<<256, 256, 0, stream>>>(list, counter, FARCAP,
                                             cnt_all, sx_all, sy_all, HWp, W, H);
        int vblocks = (int)((plane / 4 + 255) / 256);
        norm_stream<<<vblocks, 256, 0, stream>>>(cnt_all, sx_all, sy_all, out,
                                                 counter + 32, hlist, HCAP,
                                                 B, H, W);
        fill_holes<<<512, 256, 0, stream>>>(hlist, counter + 32, HCAP,
                                            cnt_all, sx_all, sy_all, out,
                                            B, H, W);
    } else if (ws_size >= 3 * plane * sizeof(float)) {
        hipMemsetAsync(d_ws, 0, 3 * plane * sizeof(float), stream);
        splat_naive_ws<<<blocks, 256, 0, stream>>>(flow, depth,
                                                   cnt_all, sx_all, sy_all,
                                                   B, H, W);
        norm_fill_mono<<<blocks, 256, 0, stream>>>(cnt_all, sx_all, sy_all,
                                                   out, B, H, W);
    }
}

// Round 15
// 188.577 us; speedup vs baseline: 1.2872x; 1.2872x over previous
//
#include <hip/hip_runtime.h>

// DepthFlowProjectionModule — B=4, H=1080, W=1920, fp32.
// Round 15: revert R14's split (failed: branchless norm_stream = same 100us
// as divide-laden norm_fill => divides/divergence never were the bottleneck;
// the invariant ~100us at 1.7 TB/s with ALL units idle = latency/issue-bound
// one-shot structure). norm_fill now GRID-STRIDE (2048 blocks, ~4 iter/thread,
// the structure the 6.3 TB/s copy ubench uses), rcp-based normalize, inline
// hole scans (proven free in R13). Planes skewed 8320B to de-alias channels.
// splat_box (R13 4-px vectorized, u64-packed 2-LDS-atomic) + scatter_far
// unchanged.

#define TW 80
#define TH 60
#define AW 81             // A-plane cols  (x0-1 .. x0+TW-1)
#define AH 61             // A-plane rows  (y0-1 .. y0+TH-1)
#define APIX (AW * AH)    // 4941 cells; u64 plane + f32 plane = 59292 B LDS
#define EW 128            // read region: gx in [x0-24, x0+103]
#define EH 112            // read region: gy in [y0-26, y0+85]
#define RX 24
#define RY 26
#define DXLO (-24)
#define DXHI 23
#define DYLO (-26)
#define DYHI 25
#define BLK 1024
#define FCAP 256          // LDS far-record staging (expected ~26/block)
#define FPSCALE 1048576.0f           // 2^20
#define FPINV   9.5367431640625e-7f  // 2^-20
#define FARCAP 400000     // global far-list capacity (expected ~45K)
#define PSKEW 2080        // floats (8320B) skew between ws planes

__global__ __launch_bounds__(BLK, 2) void splat_box(
    const float* __restrict__ flow, const float* __restrict__ depth,
    float* __restrict__ cnt_all, float* __restrict__ sx_all,
    float* __restrict__ sy_all,
    unsigned* __restrict__ counter, float4* __restrict__ list, int cap,
    int B, int H, int W)
{
    __shared__ unsigned long long lpk[APIX];   // (sx_fixed<<32)|sy_fixed, biased
    __shared__ float lcf[APIX];                // cnt = sum of m*w
    __shared__ float4 fstage[FCAP];
    __shared__ unsigned fcnt, fbase;

    int tid = threadIdx.x;
    for (int q = tid; q < APIX; q += BLK) { lpk[q] = 0ULL; lcf[q] = 0.0f; }
    if (tid == 0) fcnt = 0;
    __syncthreads();

    int x0 = blockIdx.x * TW;
    int y0 = blockIdx.y * TH;
    int b  = blockIdx.z;
    int HWp = H * W;
    const float* fb = flow + (size_t)b * 2 * HWp;
    const float* db = depth + (size_t)b * HWp;
    float* cm  = cnt_all + (size_t)b * HWp;
    float* sxm = sx_all + (size_t)b * HWp;
    float* sym = sy_all + (size_t)b * HWp;

    // 4 px per thread: 32 col-groups x 32 rows per k-iteration
    int cg = tid & 31;            // column group (4 px each)
    int rr = tid >> 5;            // row within the 32-row slab
    int gx0 = x0 - RX + cg * 4;   // group base col (multiple of 4)
    bool gx_ok = (unsigned)gx0 < (unsigned)W;   // whole group in/out (W%4==0)

    #pragma unroll
    for (int k = 0; k < 4; ++k) {
        int ey = k * 32 + rr;
        if (ey >= EH) continue;                 // only k=3, rr>=16
        int gy = y0 - RY + ey;
        if (!gx_ok || (unsigned)gy >= (unsigned)H) continue;
        int p = gy * W + gx0;
        float4 fx4 = *(const float4*)(fb + p);
        float4 fy4 = *(const float4*)(fb + HWp + p);
        float4 w4  = *(const float4*)(db + p);
        const float* fxp = (const float*)&fx4;
        const float* fyp = (const float*)&fy4;
        const float* wp  = (const float*)&w4;
        #pragma unroll
        for (int j = 0; j < 4; ++j) {
            int gx = gx0 + j;
            float fx = fxp[j], fy = fyp[j];
            float x2 = (float)gx + fx;
            float y2 = (float)gy + fy;
            if (!(x2 >= 0.0f && y2 >= 0.0f &&
                  x2 <= (float)(W - 1) && y2 <= (float)(H - 1)))
                continue;
            float w = wp[j];
            int ixL = min((int)x2, W - 1);  // x2>=0 -> trunc == floor == astype+clip
            int iyT = min((int)y2, H - 1);
            int dx = ixL - gx;
            int dy = iyT - gy;
            bool near = (dx >= DXLO) & (dx <= DXHI) & (dy >= DYLO) & (dy <= DYHI);
            if (near) {
                int ax = ixL - (x0 - 1);
                int ay = iyT - (y0 - 1);
                if ((unsigned)ax < (unsigned)AW && (unsigned)ay < (unsigned)AH) {
                    float m = ((ixL == W - 1) ? 2.0f : 1.0f) *
                              ((iyT == H - 1) ? 2.0f : 1.0f);
                    float mw = m * w;
                    // biased-positive fixed point; near => |fx|<24, |fy|<26 < 32
                    unsigned ux = __float2uint_rn((32.0f - fx) * mw * FPSCALE);
                    unsigned uy = __float2uint_rn((32.0f - fy) * mw * FPSCALE);
                    int l = ay * AW + ax;
                    atomicAdd(&lpk[l], ((unsigned long long)ux << 32) | uy);
                    atomicAdd(&lcf[l], mw);
                }
            } else if (((unsigned)(gx - x0) < (unsigned)TW) &&
                       ((unsigned)(gy - y0) < (unsigned)TH)) {
                // far tail: stage in LDS (per-CU atomic); global fallback if full
                unsigned key = (unsigned)ixL | ((unsigned)iyT << 11) |
                               ((unsigned)b << 22);
                float4 rec = make_float4(__uint_as_float(key), w, -fx * w, -fy * w);
                unsigned li = atomicAdd(&fcnt, 1u);
                if (li < FCAP) {
                    fstage[li] = rec;
                } else {
                    unsigned gi = atomicAdd(counter, 1u);
                    if (gi < (unsigned)cap) list[gi] = rec;
                }
            }
        }
    }
    __syncthreads();

    // reserve one contiguous chunk for this block's staged far records
    if (tid == 0) {
        unsigned n = min(fcnt, (unsigned)FCAP);
        fbase = atomicAdd(counter, n);
    }
    __syncthreads();
    unsigned nst = min(fcnt, (unsigned)FCAP);
    for (unsigned q = tid; q < nst; q += BLK) {
        unsigned gi = fbase + q;
        if (gi < (unsigned)cap) list[gi] = fstage[q];
    }

    // flush: per-cell debias (exact via cnt), then 2x2 box-sum; exclusive store
    for (int q = tid; q < TW * TH; q += BLK) {
        int oyy = q / TW;
        int oxx = q - oyy * TW;
        int base = (oyy + 1) * AW + (oxx + 1);
        float c = 0.0f, sx = 0.0f, sy = 0.0f;
        #pragma unroll
        for (int j = 0; j < 4; ++j) {
            int l = base - (j & 1) - (j >> 1) * AW;
            unsigned long long pk = lpk[l];
            float cc = lcf[l];
            float bias = 32.0f * cc;
            c  += cc;
            sx += (float)(unsigned)(pk >> 32) * FPINV - bias;
            sy += (float)(unsigned)(pk & 0xFFFFFFFFULL) * FPINV - bias;
        }
        int g = (y0 + oyy) * W + x0 + oxx;
        cm[g]  = c;
        sxm[g] = sx;
        sym[g] = sy;
    }
}

__global__ void scatter_far(const float4* __restrict__ list,
                            const unsigned* __restrict__ counter, int cap,
                            float* __restrict__ cnt_all, float* __restrict__ sx_all,
                            float* __restrict__ sy_all, int HWp, int W, int H)
{
    unsigned n = min(counter[0], (unsigned)cap);
    for (unsigned i = blockIdx.x * blockDim.x + threadIdx.x; i < n;
         i += gridDim.x * blockDim.x) {
        float4 e = list[i];
        unsigned key = __float_as_uint(e.x);
        int x = key & 2047u;
        int y = (key >> 11) & 2047u;
        int b = key >> 22;
        int ixR = min(x + 1, W - 1);
        int iyB = min(y + 1, H - 1);
        size_t base = (size_t)b * HWp;
        int i00 = y * W + x,   i01 = y * W + ixR;
        int i10 = iyB * W + x, i11 = iyB * W + ixR;
        atomicAdd(&cnt_all[base + i00], e.y);
        atomicAdd(&cnt_all[base + i01], e.y);
        atomicAdd(&cnt_all[base + i10], e.y);
        atomicAdd(&cnt_all[base + i11], e.y);
        atomicAdd(&sx_all[base + i00], e.z);
        atomicAdd(&sx_all[base + i01], e.z);
        atomicAdd(&sx_all[base + i10], e.z);
        atomicAdd(&sx_all[base + i11], e.z);
        atomicAdd(&sy_all[base + i00], e.w);
        atomicAdd(&sy_all[base + i01], e.w);
        atomicAdd(&sy_all[base + i10], e.w);
        atomicAdd(&sy_all[base + i11], e.w);
    }
}

// fused normalize + hole-fill: GRID-STRIDE float4 streaming (ubench structure)
__global__ void norm_fill(const float* __restrict__ cnt_all,
                          const float* __restrict__ sx_all,
                          const float* __restrict__ sy_all,
                          float* __restrict__ out,
                          int B, int H, int W)
{
    int HWp = H * W;
    int total4 = (B * HWp) >> 2;
    int stride = gridDim.x * blockDim.x;
    for (int t = blockIdx.x * blockDim.x + threadIdx.x; t < total4; t += stride) {
        int i4 = t << 2;
        int b = i4 / HWp;
        int r = i4 - b * HWp;          // HWp%4==0 -> all 4 px in same batch
        const float* cb  = cnt_all + (size_t)b * HWp;
        const float* sxb = sx_all + (size_t)b * HWp;
        const float* syb = sy_all + (size_t)b * HWp;
        float4 c4 = *(const float4*)(cb + r);
        float4 x4 = *(const float4*)(sxb + r);
        float4 y4 = *(const float4*)(syb + r);
        const float* cp = (const float*)&c4;
        const float* xp = (const float*)&x4;
        const float* yp = (const float*)&y4;
        float rx[4], ry[4];
        #pragma unroll
        for (int j = 0; j < 4; ++j) {
            float c = cp[j];
            if (c > 0.0f) {
                float inv = __builtin_amdgcn_rcpf(c);
                rx[j] = xp[j] * inv;
                ry[j] = yp[j] * inv;
            } else {
                int rr = r + j;
                int y = rr / W;
                int x = rr - y * W;
                float nx = 0.0f, ny = 0.0f;
                int den = 0;
                for (int xx = x - 1; xx >= 0; --xx) {
                    int q = y * W + xx; float cq = cb[q];
                    if (cq > 0.0f) {
                        float iv = __builtin_amdgcn_rcpf(cq);
                        nx += sxb[q] * iv; ny += syb[q] * iv; ++den; break;
                    }
                }
                for (int xx = x + 1; xx < W; ++xx) {
                    int q = y * W + xx; float cq = cb[q];
                    if (cq > 0.0f) {
                        float iv = __builtin_amdgcn_rcpf(cq);
                        nx += sxb[q] * iv; ny += syb[q] * iv; ++den; break;
                    }
                }
                for (int yy = y - 1; yy >= 0; --yy) {
                    int q = yy * W + x; float cq = cb[q];
                    if (cq > 0.0f) {
                        float iv = __builtin_amdgcn_rcpf(cq);
                        nx += sxb[q] * iv; ny += syb[q] * iv; ++den; break;
                    }
                }
                for (int yy = y + 1; yy < H; ++yy) {
                    int q = yy * W + x; float cq = cb[q];
                    if (cq > 0.0f) {
                        float iv = __builtin_amdgcn_rcpf(cq);
                        nx += sxb[q] * iv; ny += syb[q] * iv; ++den; break;
                    }
                }
                if (den > 0) {
                    float fd = __builtin_amdgcn_rcpf((float)den);
                    rx[j] = nx * fd; ry[j] = ny * fd;
                } else {
                    rx[j] = 0.0f; ry[j] = 0.0f;   // ref: hole & den==0 keeps 0
                }
            }
        }
        float* ob = out + (size_t)b * 2 * HWp;
        *(float4*)(ob + r)       = make_float4(rx[0], rx[1], rx[2], rx[3]);
        *(float4*)(ob + HWp + r) = make_float4(ry[0], ry[1], ry[2], ry[3]);
    }
}

// fallback (ws too small / shape mismatch): global atomics into ws planes
__global__ void splat_naive_ws(const float* __restrict__ flow,
                               const float* __restrict__ depth,
                               float* __restrict__ cnt_all,
                               float* __restrict__ sx_all,
                               float* __restrict__ sy_all,
                               int B, int H, int W)
{
    int i = blockIdx.x * blockDim.x + threadIdx.x;
    int HWp = H * W;
    if (i >= B * HWp) return;
    int b = i / HWp;
    int p = i - b * HWp;
    int y = p / W;
    int x = p - y * W;
    const float* fb = flow + (size_t)b * 2 * HWp;
    float fx = fb[p], fy = fb[HWp + p];
    float x2 = (float)x + fx, y2 = (float)y + fy;
    if (!(x2 >= 0.0f && y2 >= 0.0f && x2 <= (float)(W - 1) && y2 <= (float)(H - 1)))
        return;
    float w = depth[i];
    int ixL = min((int)x2, W - 1);
    int iyT = min((int)y2, H - 1);
    int ixR = min(ixL + 1, W - 1);
    int iyB = min(iyT + 1, H - 1);
    float ax = -fx * w, ay = -fy * w;
    size_t base = (size_t)b * HWp;
    int idx[4] = {iyT * W + ixL, iyT * W + ixR, iyB * W + ixL, iyB * W + ixR};
    #pragma unroll
    for (int c = 0; c < 4; ++c) {
        atomicAdd(&cnt_all[base + idx[c]], w);
        atomicAdd(&sx_all[base + idx[c]], ax);
        atomicAdd(&sy_all[base + idx[c]], ay);
    }
}

extern "C" void kernel_launch(void* const* d_in, const int* in_sizes, int n_in,
                              void* d_out, int out_size, void* d_ws, size_t ws_size,
                              hipStream_t stream) {
    const float* flow  = (const float*)d_in[0];   // (B,2,H,W)
    const float* depth = (const float*)d_in[1];   // (B,1,H,W)
    float* out = (float*)d_out;                   // (B,2,H,W)

    const int H = 1080, W = 1920;
    const int HWp = H * W;
    const int B = in_sizes[1] / HWp;
    const size_t plane = (size_t)B * HWp;
    const size_t ps = plane + PSKEW;   // skewed plane stride (16B-aligned)

    // ws: [cnt][skew][sx][skew][sy][256B counters][far list FARCAP*16B]
    float* cnt_all = (float*)d_ws;
    float* sx_all  = cnt_all + ps;
    float* sy_all  = cnt_all + 2 * ps;
    unsigned* counter = (unsigned*)(cnt_all + 2 * ps + plane);
    float4* list = (float4*)((char*)counter + 256);
    size_t need = (2 * ps + plane) * sizeof(float) + 256 + (size_t)FARCAP * 16;

    int blocks = (int)((plane + 255) / 256);
    bool tiled = (ws_size >= need) && (W % TW == 0) && (H % TH == 0) && (W % 4 == 0);

    if (tiled) {
        hipMemsetAsync(counter, 0, 256, stream);   // far counter only
        dim3 grid(W / TW, H / TH, B);              // 24 x 18 x 4
        splat_box<<<grid, BLK, 0, stream>>>(flow, depth, cnt_all, sx_all, sy_all,
                                            counter, list, FARCAP, B, H, W);
        scatter_far<<<256, 256, 0, stream>>>(list, counter, FARCAP,
                                             cnt_all, sx_all, sy_all, HWp, W, H);
        norm_fill<<<2048, 256, 0, stream>>>(cnt_all, sx_all, sy_all, out, B, H, W);
    } else if (ws_size >= (2 * ps + plane) * sizeof(float)) {
        hipMemsetAsync(d_ws, 0, (2 * ps + plane) * sizeof(float), stream);
        splat_naive_ws<<<blocks, 256, 0, stream>>>(flow, depth,
                                                   cnt_all, sx_all, sy_all,
                                                   B, H, W);
        norm_fill<<<2048, 256, 0, stream>>>(cnt_all, sx_all, sy_all, out, B, H, W);
    }
}

// Round 16
// 147.286 us; speedup vs baseline: 1.6480x; 1.2803x over previous
//
#include <hip/hip_runtime.h>

// DepthFlowProjectionModule — B=4, H=1080, W=1920, fp32.
// Round 16: kill the 85us norm pass. splat_box's flush already holds final
// plane values for ~96% of pixels (only far-tail corners ~180K and holes
// ~150K change later) -> flush writes normalized out directly (rcp, proven
// R15), appends flush-time holes to a compact list (reusing fstage LDS after
// far copy-out). After scatter_far finalizes planes, ONE sparse fixup kernel
// recomputes out for {far corners} U {holes} only (~330K px, idempotent,
// duplicate-safe). Deletes 166MB of norm_fill traffic for +66MB flush writes.
// splat deposit path (R13 4-px vectorized, u64-packed 2-LDS-atomic) unchanged.

#define TW 80
#define TH 60
#define AW 81             // A-plane cols  (x0-1 .. x0+TW-1)
#define AH 61             // A-plane rows  (y0-1 .. y0+TH-1)
#define APIX (AW * AH)    // 4941 cells
#define EW 128            // read region: gx in [x0-24, x0+103]
#define EH 112            // read region: gy in [y0-26, y0+85]
#define RX 24
#define RY 26
#define DXLO (-24)
#define DXHI 23
#define DYLO (-26)
#define DYHI 25
#define BLK 1024
#define FCAP 256          // LDS far-record staging (expected ~26/block)
#define HSCAP 1024        // LDS hole staging (expected ~90/block), = fstage size
#define FPSCALE 1048576.0f           // 2^20
#define FPINV   9.5367431640625e-7f  // 2^-20
#define FARCAP 400000     // global far-list capacity (expected ~45K)
#define HCAP   2000000    // global hole-list capacity (expected ~150K)
#define PSKEW 2080        // floats (8320B) skew between ws planes

__global__ __launch_bounds__(BLK, 2) void splat_box(
    const float* __restrict__ flow, const float* __restrict__ depth,
    float* __restrict__ cnt_all, float* __restrict__ sx_all,
    float* __restrict__ sy_all, float* __restrict__ out,
    unsigned* __restrict__ counter, float4* __restrict__ list, int cap,
    unsigned* __restrict__ hcounter, unsigned* __restrict__ hlist, int hcap,
    int B, int H, int W)
{
    __shared__ unsigned long long lpk[APIX];   // (sx_fixed<<32)|sy_fixed, biased
    __shared__ float lcf[APIX];                // cnt = sum of m*w
    __shared__ float4 fstage[FCAP];            // far staging; reused for holes
    __shared__ unsigned fcnt, fbase, hcnt_s, hbase_s;

    int tid = threadIdx.x;
    for (int q = tid; q < APIX; q += BLK) { lpk[q] = 0ULL; lcf[q] = 0.0f; }
    if (tid == 0) { fcnt = 0; hcnt_s = 0; }
    __syncthreads();

    int x0 = blockIdx.x * TW;
    int y0 = blockIdx.y * TH;
    int b  = blockIdx.z;
    int HWp = H * W;
    const float* fb = flow + (size_t)b * 2 * HWp;
    const float* db = depth + (size_t)b * HWp;
    float* cm  = cnt_all + (size_t)b * HWp;
    float* sxm = sx_all + (size_t)b * HWp;
    float* sym = sy_all + (size_t)b * HWp;
    float* ob  = out + (size_t)b * 2 * HWp;

    // 4 px per thread: 32 col-groups x 32 rows per k-iteration
    int cg = tid & 31;            // column group (4 px each)
    int rr = tid >> 5;            // row within the 32-row slab
    int gx0 = x0 - RX + cg * 4;   // group base col (multiple of 4)
    bool gx_ok = (unsigned)gx0 < (unsigned)W;   // whole group in/out (W%4==0)

    #pragma unroll
    for (int k = 0; k < 4; ++k) {
        int ey = k * 32 + rr;
        if (ey >= EH) continue;                 // only k=3, rr>=16
        int gy = y0 - RY + ey;
        if (!gx_ok || (unsigned)gy >= (unsigned)H) continue;
        int p = gy * W + gx0;
        float4 fx4 = *(const float4*)(fb + p);
        float4 fy4 = *(const float4*)(fb + HWp + p);
        float4 w4  = *(const float4*)(db + p);
        const float* fxp = (const float*)&fx4;
        const float* fyp = (const float*)&fy4;
        const float* wp  = (const float*)&w4;
        #pragma unroll
        for (int j = 0; j < 4; ++j) {
            int gx = gx0 + j;
            float fx = fxp[j], fy = fyp[j];
            float x2 = (float)gx + fx;
            float y2 = (float)gy + fy;
            if (!(x2 >= 0.0f && y2 >= 0.0f &&
                  x2 <= (float)(W - 1) && y2 <= (float)(H - 1)))
                continue;
            float w = wp[j];
            int ixL = min((int)x2, W - 1);  // x2>=0 -> trunc == floor == astype+clip
            int iyT = min((int)y2, H - 1);
            int dx = ixL - gx;
            int dy = iyT - gy;
            bool near = (dx >= DXLO) & (dx <= DXHI) & (dy >= DYLO) & (dy <= DYHI);
            if (near) {
                int ax = ixL - (x0 - 1);
                int ay = iyT - (y0 - 1);
                if ((unsigned)ax < (unsigned)AW && (unsigned)ay < (unsigned)AH) {
                    float m = ((ixL == W - 1) ? 2.0f : 1.0f) *
                              ((iyT == H - 1) ? 2.0f : 1.0f);
                    float mw = m * w;
                    // biased-positive fixed point; near => |fx|<24, |fy|<26 < 32
                    unsigned ux = __float2uint_rn((32.0f - fx) * mw * FPSCALE);
                    unsigned uy = __float2uint_rn((32.0f - fy) * mw * FPSCALE);
                    int l = ay * AW + ax;
                    atomicAdd(&lpk[l], ((unsigned long long)ux << 32) | uy);
                    atomicAdd(&lcf[l], mw);
                }
            } else if (((unsigned)(gx - x0) < (unsigned)TW) &&
                       ((unsigned)(gy - y0) < (unsigned)TH)) {
                // far tail: stage in LDS (per-CU atomic); global fallback if full
                unsigned key = (unsigned)ixL | ((unsigned)iyT << 11) |
                               ((unsigned)b << 22);
                float4 rec = make_float4(__uint_as_float(key), w, -fx * w, -fy * w);
                unsigned li = atomicAdd(&fcnt, 1u);
                if (li < FCAP) {
                    fstage[li] = rec;
                } else {
                    unsigned gi = atomicAdd(counter, 1u);
                    if (gi < (unsigned)cap) list[gi] = rec;
                }
            }
        }
    }
    __syncthreads();

    // reserve one contiguous chunk for this block's staged far records
    if (tid == 0) {
        unsigned n = min(fcnt, (unsigned)FCAP);
        fbase = atomicAdd(counter, n);
    }
    __syncthreads();
    unsigned nst = min(fcnt, (unsigned)FCAP);
    for (unsigned q = tid; q < nst; q += BLK) {
        unsigned gi = fbase + q;
        if (gi < (unsigned)cap) list[gi] = fstage[q];
    }
    __syncthreads();   // fstage fully drained; safe to reuse as hole stage
    unsigned* hstage = (unsigned*)fstage;   // HSCAP entries

    // flush: debias, 2x2 box-sum, write planes AND normalized out;
    // flush-time holes (cnt==0) -> out=0 + hole list
    for (int q = tid; q < TW * TH; q += BLK) {
        int oyy = q / TW;
        int oxx = q - oyy * TW;
        int base = (oyy + 1) * AW + (oxx + 1);
        float c = 0.0f, sx = 0.0f, sy = 0.0f;
        #pragma unroll
        for (int j = 0; j < 4; ++j) {
            int l = base - (j & 1) - (j >> 1) * AW;
            unsigned long long pk = lpk[l];
            float cc = lcf[l];
            float bias = 32.0f * cc;
            c  += cc;
            sx += (float)(unsigned)(pk >> 32) * FPINV - bias;
            sy += (float)(unsigned)(pk & 0xFFFFFFFFULL) * FPINV - bias;
        }
        int g = (y0 + oyy) * W + x0 + oxx;
        cm[g]  = c;
        sxm[g] = sx;
        sym[g] = sy;
        float rx = 0.0f, ry = 0.0f;
        if (c > 0.0f) {
            float inv = __builtin_amdgcn_rcpf(c);
            rx = sx * inv;
            ry = sy * inv;
        } else {
            unsigned li = atomicAdd(&hcnt_s, 1u);
            unsigned gidx = (unsigned)(b * HWp + g);
            if (li < HSCAP) {
                hstage[li] = gidx;
            } else {
                unsigned gi = atomicAdd(hcounter, 1u);
                if (gi < (unsigned)hcap) hlist[gi] = gidx;
            }
        }
        ob[g] = rx;
        ob[HWp + g] = ry;
    }
    __syncthreads();
    if (tid == 0) {
        unsigned n = min(hcnt_s, (unsigned)HSCAP);
        hbase_s = atomicAdd(hcounter, n);
    }
    __syncthreads();
    unsigned nh = min(hcnt_s, (unsigned)HSCAP);
    for (unsigned q = tid; q < nh; q += BLK) {
        unsigned gi = hbase_s + q;
        if (gi < (unsigned)hcap) hlist[gi] = hstage[q];
    }
}

__global__ void scatter_far(const float4* __restrict__ list,
                            const unsigned* __restrict__ counter, int cap,
                            float* __restrict__ cnt_all, float* __restrict__ sx_all,
                            float* __restrict__ sy_all, int HWp, int W, int H)
{
    unsigned n = min(counter[0], (unsigned)cap);
    for (unsigned i = blockIdx.x * blockDim.x + threadIdx.x; i < n;
         i += gridDim.x * blockDim.x) {
        float4 e = list[i];
        unsigned key = __float_as_uint(e.x);
        int x = key & 2047u;
        int y = (key >> 11) & 2047u;
        int b = key >> 22;
        int ixR = min(x + 1, W - 1);
        int iyB = min(y + 1, H - 1);
        size_t base = (size_t)b * HWp;
        int i00 = y * W + x,   i01 = y * W + ixR;
        int i10 = iyB * W + x, i11 = iyB * W + ixR;
        atomicAdd(&cnt_all[base + i00], e.y);
        atomicAdd(&cnt_all[base + i01], e.y);
        atomicAdd(&cnt_all[base + i10], e.y);
        atomicAdd(&cnt_all[base + i11], e.y);
        atomicAdd(&sx_all[base + i00], e.z);
        atomicAdd(&sx_all[base + i01], e.z);
        atomicAdd(&sx_all[base + i10], e.z);
        atomicAdd(&sx_all[base + i11], e.z);
        atomicAdd(&sy_all[base + i00], e.w);
        atomicAdd(&sy_all[base + i01], e.w);
        atomicAdd(&sy_all[base + i10], e.w);
        atomicAdd(&sy_all[base + i11], e.w);
    }
}

// sparse fixup: recompute out for {far corners} U {flush-time holes} from
// FINAL planes. Idempotent; duplicate entries write identical bits.
__global__ void fixup(const float4* __restrict__ list,
                      const unsigned* __restrict__ counter, int cap,
                      const unsigned* __restrict__ hlist,
                      const unsigned* __restrict__ hcounter, int hcap,
                      const float* __restrict__ cnt_all,
                      const float* __restrict__ sx_all,
                      const float* __restrict__ sy_all,
                      float* __restrict__ out,
                      int B, int H, int W)
{
    int HWp = H * W;
    unsigned nf = min(counter[0], (unsigned)cap);
    unsigned nh = min(hcounter[0], (unsigned)hcap);
    unsigned total = nf * 4 + nh;
    for (unsigned t = blockIdx.x * blockDim.x + threadIdx.x; t < total;
         t += gridDim.x * blockDim.x) {
        int b, r;
        if (t < nf * 4) {
            float4 e = list[t >> 2];
            unsigned key = __float_as_uint(e.x);
            int x = key & 2047u;
            int y = (key >> 11) & 2047u;
            b = key >> 22;
            int ix = min(x + (int)(t & 1u), W - 1);
            int iy = min(y + (int)((t >> 1) & 1u), H - 1);
            r = iy * W + ix;
        } else {
            unsigned i = hlist[t - nf * 4];
            b = i / HWp;
            r = (int)(i - (unsigned)b * HWp);
        }
        const float* cb  = cnt_all + (size_t)b * HWp;
        const float* sxb = sx_all + (size_t)b * HWp;
        const float* syb = sy_all + (size_t)b * HWp;
        float c = cb[r];
        float rx, ry;
        if (c > 0.0f) {
            float inv = __builtin_amdgcn_rcpf(c);
            rx = sxb[r] * inv;
            ry = syb[r] * inv;
        } else {
            int y = r / W;
            int x = r - y * W;
            float nx = 0.0f, ny = 0.0f;
            int den = 0;
            for (int xx = x - 1; xx >= 0; --xx) {
                int q = y * W + xx; float cq = cb[q];
                if (cq > 0.0f) {
                    float iv = __builtin_amdgcn_rcpf(cq);
                    nx += sxb[q] * iv; ny += syb[q] * iv; ++den; break;
                }
            }
            for (int xx = x + 1; xx < W; ++xx) {
                int q = y * W + xx; float cq = cb[q];
                if (cq > 0.0f) {
                    float iv = __builtin_amdgcn_rcpf(cq);
                    nx += sxb[q] * iv; ny += syb[q] * iv; ++den; break;
                }
            }
            for (int yy = y - 1; yy >= 0; --yy) {
                int q = yy * W + x; float cq = cb[q];
                if (cq > 0.0f) {
                    float iv = __builtin_amdgcn_rcpf(cq);
                    nx += sxb[q] * iv; ny += syb[q] * iv; ++den; break;
                }
            }
            for (int yy = y + 1; yy < H; ++yy) {
                int q = yy * W + x; float cq = cb[q];
                if (cq > 0.0f) {
                    float iv = __builtin_amdgcn_rcpf(cq);
                    nx += sxb[q] * iv; ny += syb[q] * iv; ++den; break;
                }
            }
            if (den > 0) {
                float fd = __builtin_amdgcn_rcpf((float)den);
                rx = nx * fd; ry = ny * fd;
            } else {
                rx = 0.0f; ry = 0.0f;   // ref: hole & den==0 keeps 0
            }
        }
        float* ob = out + (size_t)b * 2 * HWp;
        ob[r] = rx;
        ob[HWp + r] = ry;
    }
}

// ---- fallback path (ws too small / shape mismatch) ----
__global__ void splat_naive_ws(const float* __restrict__ flow,
                               const float* __restrict__ depth,
                               float* __restrict__ cnt_all,
                               float* __restrict__ sx_all,
                               float* __restrict__ sy_all,
                               int B, int H, int W)
{
    int i = blockIdx.x * blockDim.x + threadIdx.x;
    int HWp = H * W;
    if (i >= B * HWp) return;
    int b = i / HWp;
    int p = i - b * HWp;
    int y = p / W;
    int x = p - y * W;
    const float* fb = flow + (size_t)b * 2 * HWp;
    float fx = fb[p], fy = fb[HWp + p];
    float x2 = (float)x + fx, y2 = (float)y + fy;
    if (!(x2 >= 0.0f && y2 >= 0.0f && x2 <= (float)(W - 1) && y2 <= (float)(H - 1)))
        return;
    float w = depth[i];
    int ixL = min((int)x2, W - 1);
    int iyT = min((int)y2, H - 1);
    int ixR = min(ixL + 1, W - 1);
    int iyB = min(iyT + 1, H - 1);
    float ax = -fx * w, ay = -fy * w;
    size_t base = (size_t)b * HWp;
    int idx[4] = {iyT * W + ixL, iyT * W + ixR, iyB * W + ixL, iyB * W + ixR};
    #pragma unroll
    for (int c = 0; c < 4; ++c) {
        atomicAdd(&cnt_all[base + idx[c]], w);
        atomicAdd(&sx_all[base + idx[c]], ax);
        atomicAdd(&sy_all[base + idx[c]], ay);
    }
}

__global__ void norm_fill_mono(const float* __restrict__ cnt_all,
                               const float* __restrict__ sx_all,
                               const float* __restrict__ sy_all,
                               float* __restrict__ out,
                               int B, int H, int W)
{
    int HWp = H * W;
    int total = B * HWp;
    int stride = gridDim.x * blockDim.x;
    for (int i = blockIdx.x * blockDim.x + threadIdx.x; i < total; i += stride) {
        int b = i / HWp;
        int r = i - b * HWp;
        const float* cb  = cnt_all + (size_t)b * HWp;
        const float* sxb = sx_all + (size_t)b * HWp;
        const float* syb = sy_all + (size_t)b * HWp;
        float c = cb[r];
        float rx, ry;
        if (c > 0.0f) {
            rx = sxb[r] / c;
            ry = syb[r] / c;
        } else {
            int y = r / W;
            int x = r - y * W;
            float nx = 0.0f, ny = 0.0f;
            int den = 0;
            for (int xx = x - 1; xx >= 0; --xx) {
                int q = y * W + xx; float cq = cb[q];
                if (cq > 0.0f) { nx += sxb[q] / cq; ny += syb[q] / cq; ++den; break; }
            }
            for (int xx = x + 1; xx < W; ++xx) {
                int q = y * W + xx; float cq = cb[q];
                if (cq > 0.0f) { nx += sxb[q] / cq; ny += syb[q] / cq; ++den; break; }
            }
            for (int yy = y - 1; yy >= 0; --yy) {
                int q = yy * W + x; float cq = cb[q];
                if (cq > 0.0f) { nx += sxb[q] / cq; ny += syb[q] / cq; ++den; break; }
            }
            for (int yy = y + 1; yy < H; ++yy) {
                int q = yy * W + x; float cq = cb[q];
                if (cq > 0.0f) { nx += sxb[q] / cq; ny += syb[q] / cq; ++den; break; }
            }
            if (den > 0) { float fd = (float)den; rx = nx / fd; ry = ny / fd; }
            else         { rx = 0.0f; ry = 0.0f; }
        }
        float* ob = out + (size_t)b * 2 * HWp;
        ob[r] = rx;
        ob[HWp + r] = ry;
    }
}

extern "C" void kernel_launch(void* const* d_in, const int* in_sizes, int n_in,
                              void* d_out, int out_size, void* d_ws, size_t ws_size,
                              hipStream_t stream) {
    const float* flow  = (const float*)d_in[0];   // (B,2,H,W)
    const float* depth = (const float*)d_in[1];   // (B,1,H,W)
    float* out = (float*)d_out;                   // (B,2,H,W)

    const int H = 1080, W = 1920;
    const int HWp = H * W;
    const int B = in_sizes[1] / HWp;
    const size_t plane = (size_t)B * HWp;
    const size_t ps = plane + PSKEW;   // skewed plane stride (16B-aligned)

    // ws: [cnt][skew][sx][skew][sy][256B counters][far FARCAP*16][holes HCAP*4]
    float* cnt_all = (float*)d_ws;
    float* sx_all  = cnt_all + ps;
    float* sy_all  = cnt_all + 2 * ps;
    unsigned* counter = (unsigned*)(cnt_all + 2 * ps + plane); // [0]=far [32]=hole
    float4* list = (float4*)((char*)counter + 256);
    unsigned* hlist = (unsigned*)((char*)list + (size_t)FARCAP * 16);
    size_t need = (2 * ps + plane) * sizeof(float) + 256 +
                  (size_t)FARCAP * 16 + (size_t)HCAP * 4;

    int blocks = (int)((plane + 255) / 256);
    bool tiled = (ws_size >= need) && (W % TW == 0) && (H % TH == 0) && (W % 4 == 0);

    if (tiled) {
        hipMemsetAsync(counter, 0, 256, stream);   // far + hole counters
        dim3 grid(W / TW, H / TH, B);              // 24 x 18 x 4
        splat_box<<<grid, BLK, 0, stream>>>(flow, depth, cnt_all, sx_all, sy_all,
                                            out, counter, list, FARCAP,
                                            counter + 32, hlist, HCAP, B, H, W);
        scatter_far<<<256, 256, 0, stream>>>(list, counter, FARCAP,
                                             cnt_all, sx_all, sy_all, HWp, W, H);
        fixup<<<512, 256, 0, stream>>>(list, counter, FARCAP,
                                       hlist, counter + 32, HCAP,
                                       cnt_all, sx_all, sy_all, out, B, H, W);
    } else if (ws_size >= (2 * ps + plane) * sizeof(float)) {
        hipMemsetAsync(d_ws, 0, (2 * ps + plane) * sizeof(float), stream);
        splat_naive_ws<<<blocks, 256, 0, stream>>>(flow, depth,
                                                   cnt_all, sx_all, sy_all,
                                                   B, H, W);
        norm_fill_mono<<<2048, 256, 0, stream>>>(cnt_all, sx_all, sy_all,
                                                 out, B, H, W);
    }
}

// Round 17
// 140.237 us; speedup vs baseline: 1.7309x; 1.0503x over previous
//
#include <hip/hip_runtime.h>

// DepthFlowProjectionModule — B=4, H=1080, W=1920, fp32.
// Round 17: shrink the sparse tail. (1) y-halo 26->30 (EH=120=15x1024 exact,
// LDS unchanged): y-far tail drops ~6x => far records -30%. (2) fixup
// processes 1 thread per far RECORD (4 corners share cache lines; corners
// always covered -> pure normalize). Core structure proven in R16: splat
// flush writes normalized out directly + hole list; scatter_far finalizes
// planes; sparse fixup recomputes {far corners} U {holes} only.

#define TW 80
#define TH 60
#define AW 81             // A-plane cols  (x0-1 .. x0+TW-1)
#define AH 61             // A-plane rows  (y0-1 .. y0+TH-1)
#define APIX (AW * AH)    // 4941 cells
#define EW 128            // read region: gx in [x0-24, x0+103]
#define EH 120            // read region: gy in [y0-30, y0+89]; EW*EH = 15*1024
#define RX 24
#define RY 30
#define DXLO (-24)
#define DXHI 23
#define DYLO (-30)
#define DYHI 29
#define BLK 1024
#define FCAP 256          // LDS far-record staging (expected ~20/block)
#define HSCAP 1024        // LDS hole staging (expected ~90/block)
#define FPSCALE 1048576.0f           // 2^20
#define FPINV   9.5367431640625e-7f  // 2^-20
#define FARCAP 400000     // global far-list capacity (expected ~30K)
#define HCAP   2000000    // global hole-list capacity (expected ~150K)
#define PSKEW 2080        // floats (8320B) skew between ws planes

__global__ __launch_bounds__(BLK, 2) void splat_box(
    const float* __restrict__ flow, const float* __restrict__ depth,
    float* __restrict__ cnt_all, float* __restrict__ sx_all,
    float* __restrict__ sy_all, float* __restrict__ out,
    unsigned* __restrict__ counter, float4* __restrict__ list, int cap,
    unsigned* __restrict__ hcounter, unsigned* __restrict__ hlist, int hcap,
    int B, int H, int W)
{
    __shared__ unsigned long long lpk[APIX];   // (sx_fixed<<32)|sy_fixed, biased
    __shared__ float lcf[APIX];                // cnt = sum of m*w
    __shared__ float4 fstage[FCAP];            // far staging; reused for holes
    __shared__ unsigned fcnt, fbase, hcnt_s, hbase_s;

    int tid = threadIdx.x;
    for (int q = tid; q < APIX; q += BLK) { lpk[q] = 0ULL; lcf[q] = 0.0f; }
    if (tid == 0) { fcnt = 0; hcnt_s = 0; }
    __syncthreads();

    int x0 = blockIdx.x * TW;
    int y0 = blockIdx.y * TH;
    int b  = blockIdx.z;
    int HWp = H * W;
    const float* fb = flow + (size_t)b * 2 * HWp;
    const float* db = depth + (size_t)b * HWp;
    float* cm  = cnt_all + (size_t)b * HWp;
    float* sxm = sx_all + (size_t)b * HWp;
    float* sym = sy_all + (size_t)b * HWp;
    float* ob  = out + (size_t)b * 2 * HWp;

    // 4 px per thread: 32 col-groups x 32 rows per slab; 4 slabs cover EH=120
    int cg = tid & 31;            // column group (4 px each)
    int rr = tid >> 5;            // row within the 32-row slab
    int gx0 = x0 - RX + cg * 4;   // group base col (multiple of 4)
    bool gx_ok = (unsigned)gx0 < (unsigned)W;   // whole group in/out (W%4==0)

    #pragma unroll
    for (int k = 0; k < 4; ++k) {
        int ey = k * 32 + rr;
        if (ey >= EH) continue;                 // only k=3, rr>=24
        int gy = y0 - RY + ey;
        if (!gx_ok || (unsigned)gy >= (unsigned)H) continue;
        int p = gy * W + gx0;
        float4 fx4 = *(const float4*)(fb + p);
        float4 fy4 = *(const float4*)(fb + HWp + p);
        float4 w4  = *(const float4*)(db + p);
        const float* fxp = (const float*)&fx4;
        const float* fyp = (const float*)&fy4;
        const float* wp  = (const float*)&w4;
        #pragma unroll
        for (int j = 0; j < 4; ++j) {
            int gx = gx0 + j;
            float fx = fxp[j], fy = fyp[j];
            float x2 = (float)gx + fx;
            float y2 = (float)gy + fy;
            if (!(x2 >= 0.0f && y2 >= 0.0f &&
                  x2 <= (float)(W - 1) && y2 <= (float)(H - 1)))
                continue;
            float w = wp[j];
            int ixL = min((int)x2, W - 1);  // x2>=0 -> trunc == floor == astype+clip
            int iyT = min((int)y2, H - 1);
            int dx = ixL - gx;
            int dy = iyT - gy;
            bool near = (dx >= DXLO) & (dx <= DXHI) & (dy >= DYLO) & (dy <= DYHI);
            if (near) {
                int ax = ixL - (x0 - 1);
                int ay = iyT - (y0 - 1);
                if ((unsigned)ax < (unsigned)AW && (unsigned)ay < (unsigned)AH) {
                    float m = ((ixL == W - 1) ? 2.0f : 1.0f) *
                              ((iyT == H - 1) ? 2.0f : 1.0f);
                    float mw = m * w;
                    // biased-positive fixed point; near => |fx|<25, |fy|<31 < 32
                    unsigned ux = __float2uint_rn((32.0f - fx) * mw * FPSCALE);
                    unsigned uy = __float2uint_rn((32.0f - fy) * mw * FPSCALE);
                    int l = ay * AW + ax;
                    atomicAdd(&lpk[l], ((unsigned long long)ux << 32) | uy);
                    atomicAdd(&lcf[l], mw);
                }
            } else if (((unsigned)(gx - x0) < (unsigned)TW) &&
                       ((unsigned)(gy - y0) < (unsigned)TH)) {
                // far tail: stage in LDS (per-CU atomic); global fallback if full
                unsigned key = (unsigned)ixL | ((unsigned)iyT << 11) |
                               ((unsigned)b << 22);
                float4 rec = make_float4(__uint_as_float(key), w, -fx * w, -fy * w);
                unsigned li = atomicAdd(&fcnt, 1u);
                if (li < FCAP) {
                    fstage[li] = rec;
                } else {
                    unsigned gi = atomicAdd(counter, 1u);
                    if (gi < (unsigned)cap) list[gi] = rec;
                }
            }
        }
    }
    __syncthreads();

    // reserve one contiguous chunk for this block's staged far records
    if (tid == 0) {
        unsigned n = min(fcnt, (unsigned)FCAP);
        fbase = atomicAdd(counter, n);
    }
    __syncthreads();
    unsigned nst = min(fcnt, (unsigned)FCAP);
    for (unsigned q = tid; q < nst; q += BLK) {
        unsigned gi = fbase + q;
        if (gi < (unsigned)cap) list[gi] = fstage[q];
    }
    __syncthreads();   // fstage fully drained; safe to reuse as hole stage
    unsigned* hstage = (unsigned*)fstage;   // HSCAP entries

    // flush: debias, 2x2 box-sum, write planes AND normalized out;
    // flush-time holes (cnt==0) -> out=0 + hole list
    for (int q = tid; q < TW * TH; q += BLK) {
        int oyy = q / TW;
        int oxx = q - oyy * TW;
        int base = (oyy + 1) * AW + (oxx + 1);
        float c = 0.0f, sx = 0.0f, sy = 0.0f;
        #pragma unroll
        for (int j = 0; j < 4; ++j) {
            int l = base - (j & 1) - (j >> 1) * AW;
            unsigned long long pk = lpk[l];
            float cc = lcf[l];
            float bias = 32.0f * cc;
            c  += cc;
            sx += (float)(unsigned)(pk >> 32) * FPINV - bias;
            sy += (float)(unsigned)(pk & 0xFFFFFFFFULL) * FPINV - bias;
        }
        int g = (y0 + oyy) * W + x0 + oxx;
        cm[g]  = c;
        sxm[g] = sx;
        sym[g] = sy;
        float rx = 0.0f, ry = 0.0f;
        if (c > 0.0f) {
            float inv = __builtin_amdgcn_rcpf(c);
            rx = sx * inv;
            ry = sy * inv;
        } else {
            unsigned li = atomicAdd(&hcnt_s, 1u);
            unsigned gidx = (unsigned)(b * HWp + g);
            if (li < HSCAP) {
                hstage[li] = gidx;
            } else {
                unsigned gi = atomicAdd(hcounter, 1u);
                if (gi < (unsigned)hcap) hlist[gi] = gidx;
            }
        }
        ob[g] = rx;
        ob[HWp + g] = ry;
    }
    __syncthreads();
    if (tid == 0) {
        unsigned n = min(hcnt_s, (unsigned)HSCAP);
        hbase_s = atomicAdd(hcounter, n);
    }
    __syncthreads();
    unsigned nh = min(hcnt_s, (unsigned)HSCAP);
    for (unsigned q = tid; q < nh; q += BLK) {
        unsigned gi = hbase_s + q;
        if (gi < (unsigned)hcap) hlist[gi] = hstage[q];
    }
}

__global__ void scatter_far(const float4* __restrict__ list,
                            const unsigned* __restrict__ counter, int cap,
                            float* __restrict__ cnt_all, float* __restrict__ sx_all,
                            float* __restrict__ sy_all, int HWp, int W, int H)
{
    unsigned n = min(counter[0], (unsigned)cap);
    for (unsigned i = blockIdx.x * blockDim.x + threadIdx.x; i < n;
         i += gridDim.x * blockDim.x) {
        float4 e = list[i];
        unsigned key = __float_as_uint(e.x);
        int x = key & 2047u;
        int y = (key >> 11) & 2047u;
        int b = key >> 22;
        int ixR = min(x + 1, W - 1);
        int iyB = min(y + 1, H - 1);
        size_t base = (size_t)b * HWp;
        int i00 = y * W + x,   i01 = y * W + ixR;
        int i10 = iyB * W + x, i11 = iyB * W + ixR;
        atomicAdd(&cnt_all[base + i00], e.y);
        atomicAdd(&cnt_all[base + i01], e.y);
        atomicAdd(&cnt_all[base + i10], e.y);
        atomicAdd(&cnt_all[base + i11], e.y);
        atomicAdd(&sx_all[base + i00], e.z);
        atomicAdd(&sx_all[base + i01], e.z);
        atomicAdd(&sx_all[base + i10], e.z);
        atomicAdd(&sx_all[base + i11], e.z);
        atomicAdd(&sy_all[base + i00], e.w);
        atomicAdd(&sy_all[base + i01], e.w);
        atomicAdd(&sy_all[base + i10], e.w);
        atomicAdd(&sy_all[base + i11], e.w);
    }
}

// sparse fixup: recompute out for {far corners} U {flush-time holes} from
// FINAL planes. 1 thread per far RECORD (corners share cache lines; corners
// always covered since w>0 was added). Idempotent; duplicates benign.
__global__ void fixup(const float4* __restrict__ list,
                      const unsigned* __restrict__ counter, int cap,
                      const unsigned* __restrict__ hlist,
                      const unsigned* __restrict__ hcounter, int hcap,
                      const float* __restrict__ cnt_all,
                      const float* __restrict__ sx_all,
                      const float* __restrict__ sy_all,
                      float* __restrict__ out,
                      int B, int H, int W)
{
    int HWp = H * W;
    unsigned nf = min(counter[0], (unsigned)cap);
    unsigned nh = min(hcounter[0], (unsigned)hcap);
    unsigned total = nf + nh;
    for (unsigned t = blockIdx.x * blockDim.x + threadIdx.x; t < total;
         t += gridDim.x * blockDim.x) {
        if (t < nf) {
            // far record: recompute all 4 corners (always covered)
            unsigned key = __float_as_uint(list[t].x);
            int x = key & 2047u;
            int y = (key >> 11) & 2047u;
            int b = key >> 22;
            const float* cb  = cnt_all + (size_t)b * HWp;
            const float* sxb = sx_all + (size_t)b * HWp;
            const float* syb = sy_all + (size_t)b * HWp;
            float* obx = out + (size_t)b * 2 * HWp;
            #pragma unroll
            for (int c = 0; c < 4; ++c) {
                int ix = min(x + (c & 1), W - 1);
                int iy = min(y + (c >> 1), H - 1);
                int r = iy * W + ix;
                float cc = cb[r];
                float inv = (cc > 0.0f) ? __builtin_amdgcn_rcpf(cc) : 0.0f;
                obx[r] = sxb[r] * inv;
                obx[HWp + r] = syb[r] * inv;
            }
        } else {
            unsigned i = hlist[t - nf];
            int b = i / HWp;
            int r = (int)(i - (unsigned)b * HWp);
            const float* cb  = cnt_all + (size_t)b * HWp;
            const float* sxb = sx_all + (size_t)b * HWp;
            const float* syb = sy_all + (size_t)b * HWp;
            float c = cb[r];
            float rx, ry;
            if (c > 0.0f) {
                // covered by far contributions after flush
                float inv = __builtin_amdgcn_rcpf(c);
                rx = sxb[r] * inv;
                ry = syb[r] * inv;
            } else {
                int y = r / W;
                int x = r - y * W;
                float nx = 0.0f, ny = 0.0f;
                int den = 0;
                for (int xx = x - 1; xx >= 0; --xx) {
                    int q = y * W + xx; float cq = cb[q];
                    if (cq > 0.0f) {
                        float iv = __builtin_amdgcn_rcpf(cq);
                        nx += sxb[q] * iv; ny += syb[q] * iv; ++den; break;
                    }
                }
                for (int xx = x + 1; xx < W; ++xx) {
                    int q = y * W + xx; float cq = cb[q];
                    if (cq > 0.0f) {
                        float iv = __builtin_amdgcn_rcpf(cq);
                        nx += sxb[q] * iv; ny += syb[q] * iv; ++den; break;
                    }
                }
                for (int yy = y - 1; yy >= 0; --yy) {
                    int q = yy * W + x; float cq = cb[q];
                    if (cq > 0.0f) {
                        float iv = __builtin_amdgcn_rcpf(cq);
                        nx += sxb[q] * iv; ny += syb[q] * iv; ++den; break;
                    }
                }
                for (int yy = y + 1; yy < H; ++yy) {
                    int q = yy * W + x; float cq = cb[q];
                    if (cq > 0.0f) {
                        float iv = __builtin_amdgcn_rcpf(cq);
                        nx += sxb[q] * iv; ny += syb[q] * iv; ++den; break;
                    }
                }
                if (den > 0) {
                    float fd = __builtin_amdgcn_rcpf((float)den);
                    rx = nx * fd; ry = ny * fd;
                } else {
                    rx = 0.0f; ry = 0.0f;   // ref: hole & den==0 keeps 0
                }
            }
            float* ob = out + (size_t)b * 2 * HWp;
            ob[r] = rx;
            ob[HWp + r] = ry;
        }
    }
}

// ---- fallback path (ws too small / shape mismatch) ----
__global__ void splat_naive_ws(const float* __restrict__ flow,
                               const float* __restrict__ depth,
                               float* __restrict__ cnt_all,
                               float* __restrict__ sx_all,
                               float* __restrict__ sy_all,
                               int B, int H, int W)
{
    int i = blockIdx.x * blockDim.x + threadIdx.x;
    int HWp = H * W;
    if (i >= B * HWp) return;
    int b = i / HWp;
    int p = i - b * HWp;
    int y = p / W;
    int x = p - y * W;
    const float* fb = flow + (size_t)b * 2 * HWp;
    float fx = fb[p], fy = fb[HWp + p];
    float x2 = (float)x + fx, y2 = (float)y + fy;
    if (!(x2 >= 0.0f && y2 >= 0.0f && x2 <= (float)(W - 1) && y2 <= (float)(H - 1)))
        return;
    float w = depth[i];
    int ixL = min((int)x2, W - 1);
    int iyT = min((int)y2, H - 1);
    int ixR = min(ixL + 1, W - 1);
    int iyB = min(iyT + 1, H - 1);
    float ax = -fx * w, ay = -fy * w;
    size_t base = (size_t)b * HWp;
    int idx[4] = {iyT * W + ixL, iyT * W + ixR, iyB * W + ixL, iyB * W + ixR};
    #pragma unroll
    for (int c = 0; c < 4; ++c) {
        atomicAdd(&cnt_all[base + idx[c]], w);
        atomicAdd(&sx_all[base + idx[c]], ax);
        atomicAdd(&sy_all[base + idx[c]], ay);
    }
}

__global__ void norm_fill_mono(const float* __restrict__ cnt_all,
                               const float* __restrict__ sx_all,
                               const float* __restrict__ sy_all,
                               float* __restrict__ out,
                               int B, int H, int W)
{
    int HWp = H * W;
    int total = B * HWp;
    int stride = gridDim.x * blockDim.x;
    for (int i = blockIdx.x * blockDim.x + threadIdx.x; i < total; i += stride) {
        int b = i / HWp;
        int r = i - b * HWp;
        const float* cb  = cnt_all + (size_t)b * HWp;
        const float* sxb = sx_all + (size_t)b * HWp;
        const float* syb = sy_all + (size_t)b * HWp;
        float c = cb[r];
        float rx, ry;
        if (c > 0.0f) {
            rx = sxb[r] / c;
            ry = syb[r] / c;
        } else {
            int y = r / W;
            int x = r - y * W;
            float nx = 0.0f, ny = 0.0f;
            int den = 0;
            for (int xx = x - 1; xx >= 0; --xx) {
                int q = y * W + xx; float cq = cb[q];
                if (cq > 0.0f) { nx += sxb[q] / cq; ny += syb[q] / cq; ++den; break; }
            }
            for (int xx = x + 1; xx < W; ++xx) {
                int q = y * W + xx; float cq = cb[q];
                if (cq > 0.0f) { nx += sxb[q] / cq; ny += syb[q] / cq; ++den; break; }
            }
            for (int yy = y - 1; yy >= 0; --yy) {
                int q = yy * W + x; float cq = cb[q];
                if (cq > 0.0f) { nx += sxb[q] / cq; ny += syb[q] / cq; ++den; break; }
            }
            for (int yy = y + 1; yy < H; ++yy) {
                int q = yy * W + x; float cq = cb[q];
                if (cq > 0.0f) { nx += sxb[q] / cq; ny += syb[q] / cq; ++den; break; }
            }
            if (den > 0) { float fd = (float)den; rx = nx / fd; ry = ny / fd; }
            else         { rx = 0.0f; ry = 0.0f; }
        }
        float* ob = out + (size_t)b * 2 * HWp;
        ob[r] = rx;
        ob[HWp + r] = ry;
    }
}

extern "C" void kernel_launch(void* const* d_in, const int* in_sizes, int n_in,
                              void* d_out, int out_size, void* d_ws, size_t ws_size,
                              hipStream_t stream) {
    const float* flow  = (const float*)d_in[0];   // (B,2,H,W)
    const float* depth = (const float*)d_in[1];   // (B,1,H,W)
    float* out = (float*)d_out;                   // (B,2,H,W)

    const int H = 1080, W = 1920;
    const int HWp = H * W;
    const int B = in_sizes[1] / HWp;
    const size_t plane = (size_t)B * HWp;
    const size_t ps = plane + PSKEW;   // skewed plane stride (16B-aligned)

    // ws: [cnt][skew][sx][skew][sy][256B counters][far FARCAP*16][holes HCAP*4]
    float* cnt_all = (float*)d_ws;
    float* sx_all  = cnt_all + ps;
    float* sy_all  = cnt_all + 2 * ps;
    unsigned* counter = (unsigned*)(cnt_all + 2 * ps + plane); // [0]=far [32]=hole
    float4* list = (float4*)((char*)counter + 256);
    unsigned* hlist = (unsigned*)((char*)list + (size_t)FARCAP * 16);
    size_t need = (2 * ps + plane) * sizeof(float) + 256 +
                  (size_t)FARCAP * 16 + (size_t)HCAP * 4;

    int blocks = (int)((plane + 255) / 256);
    bool tiled = (ws_size >= need) && (W % TW == 0) && (H % TH == 0) && (W % 4 == 0);

    if (tiled) {
        hipMemsetAsync(counter, 0, 256, stream);   // far + hole counters
        dim3 grid(W / TW, H / TH, B);              // 24 x 18 x 4
        splat_box<<<grid, BLK, 0, stream>>>(flow, depth, cnt_all, sx_all, sy_all,
                                            out, counter, list, FARCAP,
                                            counter + 32, hlist, HCAP, B, H, W);
        scatter_far<<<256, 256, 0, stream>>>(list, counter, FARCAP,
                                             cnt_all, sx_all, sy_all, HWp, W, H);
        fixup<<<512, 256, 0, stream>>>(list, counter, FARCAP,
                                       hlist, counter + 32, HCAP,
                                       cnt_all, sx_all, sy_all, out, B, H, W);
    } else if (ws_size >= (2 * ps + plane) * sizeof(float)) {
        hipMemsetAsync(d_ws, 0, (2 * ps + plane) * sizeof(float), stream);
        splat_naive_ws<<<blocks, 256, 0, stream>>>(flow, depth,
                                                   cnt_all, sx_all, sy_all,
                                                   B, H, W);
        norm_fill_mono<<<2048, 256, 0, stream>>>(cnt_all, sx_all, sy_all,
                                                 out, B, H, W);
    }
}